// Round 5
// baseline (154.089 us; speedup 1.0000x reference)
//
#include <hip/hip_runtime.h>
#include <hip/hip_bf16.h>

// MoE top-2 + shared expert, bf16 MFMA path. Round 5.
// vs R4: GEMMs reverted to single-buffer 2-barrier K-loop (dbuf regressed, m99/m131-140
// effect) and re-tiled to 64x128 (4 waves, 32x64 each) for ~3 blocks/CU occupancy —
// the R3/R4 profiles show 1 wave/SIMD serialization (MfmaUtil 20%, Occ 14%).
// Expert groups padded to 64 rows. R4's fast transpose kept. No atomics.

#define DIM 1024
#define NTOK 2048
#define NEXP 8
#define NENT 4096          // NTOK * 2
#define ROWS_CAP 8192      // padded grouped rows upper bound
#define MAX_TILES 128      // 64-row tiles; worst case ~104
#define MM (DIM * DIM)

typedef float f32x4 __attribute__((ext_vector_type(4)));
typedef __bf16 bf16x8 __attribute__((ext_vector_type(8)));

__device__ __forceinline__ unsigned short f2bf(float f) {
  unsigned int u = __builtin_bit_cast(unsigned int, f);
  unsigned int r = u + 0x7FFFu + ((u >> 16) & 1u);   // RNE
  return (unsigned short)(r >> 16);
}
__device__ __forceinline__ void gload_lds16(const unsigned short* g, unsigned short* l) {
  __builtin_amdgcn_global_load_lds((__attribute__((address_space(1))) const void*)g,
                                   (__attribute__((address_space(3))) void*)l, 16, 0, 0);
}

// ---------------- x -> bf16 (row NTOK is an all-zero pad row) ----------------------------------
__global__ __launch_bounds__(256) void cast_x(const float* __restrict__ x,
                                              unsigned short* __restrict__ xbf) {
  int r = blockIdx.x;                 // 0..NTOK
  int c = threadIdx.x * 4;
  ushort4 o;
  if (r < NTOK) {
    float4 v = *(const float4*)(x + (size_t)r * DIM + c);
    o.x = f2bf(v.x); o.y = f2bf(v.y); o.z = f2bf(v.z); o.w = f2bf(v.w);
  } else {
    o.x = o.y = o.z = o.w = 0;
  }
  *(ushort4*)(xbf + (size_t)r * DIM + c) = o;
}

// ---------------- weight transpose+cast: dst[n][k] = bf16(src[k][n]), 27 z-slices --------------
__global__ __launch_bounds__(256) void transpose_all(
    const float* __restrict__ w1, const float* __restrict__ w3, const float* __restrict__ w2,
    const float* __restrict__ w1s, const float* __restrict__ w3s, const float* __restrict__ w2s,
    unsigned short* __restrict__ w1t, unsigned short* __restrict__ w3t,
    unsigned short* __restrict__ w2t, unsigned short* __restrict__ w1st,
    unsigned short* __restrict__ w3st, unsigned short* __restrict__ w2st) {
  __shared__ unsigned short u[32][264];   // [n][k], pad 8 -> 528B row stride
  int z = blockIdx.z;
  const float* src; unsigned short* dst;
  if (z < 8)       { src = w1 + (size_t)z * MM;        dst = w1t + (size_t)z * MM; }
  else if (z < 16) { src = w3 + (size_t)(z - 8) * MM;  dst = w3t + (size_t)(z - 8) * MM; }
  else if (z < 24) { src = w2 + (size_t)(z - 16) * MM; dst = w2t + (size_t)(z - 16) * MM; }
  else if (z == 24){ src = w1s; dst = w1st; }
  else if (z == 25){ src = w3s; dst = w3st; }
  else             { src = w2s; dst = w2st; }
  int r0 = blockIdx.y * 256, c0 = blockIdx.x * 32;
  int tid = threadIdx.x;
  int rr = tid >> 3;              // 0..31
  int cc = (tid & 7) * 4;         // 0,4,..,28
#pragma unroll
  for (int i = 0; i < 8; i++) {
    int r = rr + i * 32;
    float4 v = *(const float4*)(src + (size_t)(r0 + r) * DIM + c0 + cc);
    u[cc + 0][r] = f2bf(v.x);
    u[cc + 1][r] = f2bf(v.y);
    u[cc + 2][r] = f2bf(v.z);
    u[cc + 3][r] = f2bf(v.w);
  }
  __syncthreads();
  int rb = (tid & 31) * 8;        // k offset, 16B chunks
  int cb = tid >> 5;              // 0..7
#pragma unroll
  for (int i = 0; i < 4; i++) {
    int c = cb + i * 8;
    uint4 v = *(const uint4*)&u[c][rb];
    *(uint4*)(dst + (size_t)(c0 + c) * DIM + r0 + rb) = v;
  }
}

// ---------------- router: fp32 logits -> softmax -> top-2 --------------------------------------
__global__ __launch_bounds__(64) void router(const float* __restrict__ x,
                                             const float* __restrict__ gw,
                                             int* __restrict__ e0, int* __restrict__ e1,
                                             float* __restrict__ s0, float* __restrict__ s1) {
  int t = blockIdx.x;
  int lane = threadIdx.x;
  const float* xr = x + (size_t)t * DIM;
  float acc[NEXP];
#pragma unroll
  for (int e = 0; e < NEXP; e++) acc[e] = 0.f;
  for (int i = 0; i < DIM / 64; i++) {
    float xv = xr[i * 64 + lane];
#pragma unroll
    for (int e = 0; e < NEXP; e++) acc[e] += xv * gw[e * DIM + i * 64 + lane];
  }
#pragma unroll
  for (int e = 0; e < NEXP; e++) {
    float v = acc[e];
    for (int o = 32; o > 0; o >>= 1) v += __shfl_xor(v, o);
    acc[e] = v;
  }
  if (lane == 0) {
    float m = acc[0];
#pragma unroll
    for (int e = 1; e < NEXP; e++) m = fmaxf(m, acc[e]);
    float ex[NEXP]; float Z = 0.f;
#pragma unroll
    for (int e = 0; e < NEXP; e++) { ex[e] = __expf(acc[e] - m); Z += ex[e]; }
    float inv = 1.f / Z;
    float sc[NEXP];
#pragma unroll
    for (int e = 0; e < NEXP; e++) sc[e] = ex[e] * inv;
    int b0 = 0; float v0 = sc[0];
#pragma unroll
    for (int e = 1; e < NEXP; e++) if (sc[e] > v0) { v0 = sc[e]; b0 = e; }
    int b1 = -1; float v1 = -1.f;
#pragma unroll
    for (int e = 0; e < NEXP; e++) if (e != b0 && sc[e] > v1) { v1 = sc[e]; b1 = e; }
    e0[t] = b0; e1[t] = b1; s0[t] = v0; s1[t] = v1;
  }
}

// ---------------- deterministic grouped build: packed uint4 scan (64-row padding) --------------
__global__ __launch_bounds__(256) void build_groups(
    const int* __restrict__ e0, const int* __restrict__ e1,
    const float* __restrict__ s0, const float* __restrict__ s1,
    int* __restrict__ gtok, float* __restrict__ gsc, int* __restrict__ row_of,
    int* __restrict__ tile_e, int* __restrict__ tile_r0, int* __restrict__ ntiles,
    int* __restrict__ base8out) {
  __shared__ unsigned int wsum[4][4];
  __shared__ int offl[256][NEXP];
  __shared__ int lrl[256][NEXP];
  int t = threadIdx.x, lane = t & 63, wave = t >> 6;

  for (int i = t; i < ROWS_CAP; i += 256) { gtok[i] = NTOK; gsc[i] = 0.f; }  // pad -> zero row

  unsigned int pc[4] = {0, 0, 0, 0};
#pragma unroll
  for (int i = 0; i < 16; i++) {
    int ent = t * 16 + i;
    int tok = ent >> 1;
    int e = (ent & 1) ? e1[tok] : e0[tok];
    unsigned int add = 1u << ((e & 1) * 16);
    int c = e >> 1;
    if (c == 0) pc[0] += add; else if (c == 1) pc[1] += add;
    else if (c == 2) pc[2] += add; else pc[3] += add;
  }
  unsigned int incl[4] = {pc[0], pc[1], pc[2], pc[3]};
#pragma unroll
  for (int o = 1; o < 64; o <<= 1) {
    unsigned int u0 = __shfl_up(incl[0], o), u1 = __shfl_up(incl[1], o);
    unsigned int u2 = __shfl_up(incl[2], o), u3 = __shfl_up(incl[3], o);
    if (lane >= o) { incl[0] += u0; incl[1] += u1; incl[2] += u2; incl[3] += u3; }
  }
  if (lane == 63) { wsum[wave][0] = incl[0]; wsum[wave][1] = incl[1];
                    wsum[wave][2] = incl[2]; wsum[wave][3] = incl[3]; }
  __syncthreads();
  unsigned int T[4], pre[4] = {0, 0, 0, 0};
#pragma unroll
  for (int c = 0; c < 4; c++)
    T[c] = wsum[0][c] + wsum[1][c] + wsum[2][c] + wsum[3][c];
#pragma unroll
  for (int w = 0; w < 3; w++)
    if (wave > w) { pre[0] += wsum[w][0]; pre[1] += wsum[w][1];
                    pre[2] += wsum[w][2]; pre[3] += wsum[w][3]; }
  int base[NEXP + 1];
  {
    int b = 0;
#pragma unroll
    for (int e = 0; e < NEXP; e++) {
      int tot = (int)((T[e >> 1] >> ((e & 1) * 16)) & 0xFFFFu);
      base[e] = b; b += (tot + 63) & ~63;
    }
    base[NEXP] = b;
  }
#pragma unroll
  for (int e = 0; e < NEXP; e++) {
    unsigned int ex = (incl[e >> 1] + pre[e >> 1] - pc[e >> 1]);
    offl[t][e] = (int)((ex >> ((e & 1) * 16)) & 0xFFFFu);
    lrl[t][e] = 0;
  }
  if (t == 0) {
    int nt = 0;
#pragma unroll
    for (int e = 0; e < NEXP; e++) {
      int tot = (int)((T[e >> 1] >> ((e & 1) * 16)) & 0xFFFFu);
      int ntl = (tot + 63) >> 6;
      for (int i = 0; i < ntl; i++) { tile_e[nt] = e; tile_r0[nt] = base[e] + i * 64; nt++; }
    }
    for (int i = 0; i < NTOK / 64; i++) { tile_e[nt] = NEXP; tile_r0[nt] = base[NEXP] + i * 64; nt++; }
    *ntiles = nt;
    *base8out = base[NEXP];
  }
  __syncthreads();   // gtok/gsc clear complete before scatter

#pragma unroll
  for (int i = 0; i < 16; i++) {
    int ent = t * 16 + i;
    int tok = ent >> 1;
    int k = ent & 1;
    int e = k ? e1[tok] : e0[tok];
    float s = k ? s1[tok] : s0[tok];
    int pos = base[e] + offl[t][e] + lrl[t][e];
    lrl[t][e]++;
    gtok[pos] = tok; gsc[pos] = s; row_of[ent] = pos;
  }
  for (int i = t; i < NTOK; i += 256) { gtok[base[NEXP] + i] = i; gsc[base[NEXP] + i] = 1.0f; }
}

// ------- fused grouped GEMM: h = silu(s*(A*W1_e)) * (s*(A*W3_e)); 64x128 tile, 4 waves ---------
// Single-buffer 2-barrier K-loop (proven best); wave = 32x64 sub-tile, acc[2][4] per GEMM.
__global__ __launch_bounds__(256) void gemm13(
    const unsigned short* __restrict__ xbf,
    const unsigned short* __restrict__ W1, const unsigned short* __restrict__ W1s,
    const unsigned short* __restrict__ W3, const unsigned short* __restrict__ W3s,
    unsigned short* __restrict__ H,
    const int* __restrict__ gtok, const float* __restrict__ gsc,
    const int* __restrict__ tile_e, const int* __restrict__ tile_r0,
    const int* __restrict__ ntiles) {
  if ((int)blockIdx.y >= *ntiles) return;
  int e = tile_e[blockIdx.y];
  int row0 = tile_r0[blockIdx.y];
  int col0 = blockIdx.x * 128;
  const unsigned short* B1 = (e < NEXP) ? (W1 + (size_t)e * MM) : W1s;
  const unsigned short* B3 = (e < NEXP) ? (W3 + (size_t)e * MM) : W3s;

  __shared__ __align__(16) unsigned short As[64 * 32];     // 4KB
  __shared__ __align__(16) unsigned short Bs1[128 * 32];   // 8KB
  __shared__ __align__(16) unsigned short Bs3[128 * 32];   // 8KB
  __shared__ float ss[64];

  int tid = threadIdx.x;
  int wave = tid >> 6, lane = tid & 63;
  int wr = (wave >> 1) * 32, wc = (wave & 1) * 64;

  if (tid < 64) ss[tid] = gsc[row0 + tid];   // synced by first K-loop barrier

  f32x4 acc1[2][4], acc3[2][4];
#pragma unroll
  for (int m = 0; m < 2; m++)
#pragma unroll
    for (int n = 0; n < 4; n++) { acc1[m][n] = f32x4{0.f,0.f,0.f,0.f}; acc3[m][n] = f32x4{0.f,0.f,0.f,0.f}; }

  int li = wave * 64 + lane;          // 16B-chunk index 0..255
  int arow = li >> 2, koff = (li & 3) * 8;
  const unsigned short* ga  = xbf + (size_t)gtok[row0 + arow] * DIM + koff;      // A: 64 rows
  const unsigned short* gb10 = B1 + (size_t)(col0 + arow) * DIM + koff;          // B rows 0..63
  const unsigned short* gb11 = B1 + (size_t)(col0 + 64 + arow) * DIM + koff;     // B rows 64..127
  const unsigned short* gb30 = B3 + (size_t)(col0 + arow) * DIM + koff;
  const unsigned short* gb31 = B3 + (size_t)(col0 + 64 + arow) * DIM + koff;
  unsigned short* lA  = As  + wave * 512;          // +lane*16B by HW
  unsigned short* lB0 = Bs1 + wave * 512;
  unsigned short* lB1 = Bs1 + 2048 + wave * 512;
  unsigned short* lC0 = Bs3 + wave * 512;
  unsigned short* lC1 = Bs3 + 2048 + wave * 512;

  int kc = lane >> 4, rl = lane & 15;

  for (int k0 = 0; k0 < DIM; k0 += 32) {
    gload_lds16(ga + k0, lA);
    gload_lds16(gb10 + k0, lB0);
    gload_lds16(gb11 + k0, lB1);
    gload_lds16(gb30 + k0, lC0);
    gload_lds16(gb31 + k0, lC1);
    __syncthreads();

    const bf16x8* Ap  = (const bf16x8*)As;
    const bf16x8* B1p = (const bf16x8*)Bs1;
    const bf16x8* B3p = (const bf16x8*)Bs3;
    bf16x8 af[2], b1f[4], b3f[4];
#pragma unroll
    for (int m = 0; m < 2; m++) af[m] = Ap[(wr + m * 16 + rl) * 4 + kc];
#pragma unroll
    for (int n = 0; n < 4; n++) { b1f[n] = B1p[(wc + n * 16 + rl) * 4 + kc];
                                  b3f[n] = B3p[(wc + n * 16 + rl) * 4 + kc]; }
#pragma unroll
    for (int m = 0; m < 2; m++)
#pragma unroll
      for (int n = 0; n < 4; n++) {
        acc1[m][n] = __builtin_amdgcn_mfma_f32_16x16x32_bf16(af[m], b1f[n], acc1[m][n], 0, 0, 0);
        acc3[m][n] = __builtin_amdgcn_mfma_f32_16x16x32_bf16(af[m], b3f[n], acc3[m][n], 0, 0, 0);
      }
    __syncthreads();
  }

  int rj = lane >> 4, cl = lane & 15;
#pragma unroll
  for (int m = 0; m < 2; m++)
#pragma unroll
    for (int n = 0; n < 4; n++)
#pragma unroll
      for (int j = 0; j < 4; j++) {
        int lr = wr + m * 16 + rj * 4 + j;
        float s = ss[lr];
        float a = s * acc1[m][n][j];
        float g = s * acc3[m][n][j];
        float si = a / (1.f + __expf(-a));
        H[(size_t)(row0 + lr) * DIM + (col0 + wc + n * 16 + cl)] = f2bf(si * g);
      }
}

// ---------------- grouped GEMM: rout = H * W2_e (fp32 out); 64x128 tile ------------------------
__global__ __launch_bounds__(256) void gemm2(
    const unsigned short* __restrict__ A, const unsigned short* __restrict__ W,
    const unsigned short* __restrict__ Wsh, float* __restrict__ C,
    const int* __restrict__ tile_e, const int* __restrict__ tile_r0,
    const int* __restrict__ ntiles) {
  if ((int)blockIdx.y >= *ntiles) return;
  int e = tile_e[blockIdx.y];
  int row0 = tile_r0[blockIdx.y];
  int col0 = blockIdx.x * 128;
  const unsigned short* B = (e < NEXP) ? (W + (size_t)e * MM) : Wsh;

  __shared__ __align__(16) unsigned short As[64 * 32];
  __shared__ __align__(16) unsigned short Bs[128 * 32];

  int tid = threadIdx.x;
  int wave = tid >> 6, lane = tid & 63;
  int wr = (wave >> 1) * 32, wc = (wave & 1) * 64;

  f32x4 acc[2][4];
#pragma unroll
  for (int m = 0; m < 2; m++)
#pragma unroll
    for (int n = 0; n < 4; n++) acc[m][n] = f32x4{0.f, 0.f, 0.f, 0.f};

  int li = wave * 64 + lane;
  int arow = li >> 2, koff = (li & 3) * 8;
  const unsigned short* ga  = A + (size_t)(row0 + arow) * DIM + koff;
  const unsigned short* gb0 = B + (size_t)(col0 + arow) * DIM + koff;
  const unsigned short* gb1 = B + (size_t)(col0 + 64 + arow) * DIM + koff;
  unsigned short* lA  = As + wave * 512;
  unsigned short* lB0 = Bs + wave * 512;
  unsigned short* lB1 = Bs + 2048 + wave * 512;

  int kc = lane >> 4, rl = lane & 15;

  for (int k0 = 0; k0 < DIM; k0 += 32) {
    gload_lds16(ga + k0, lA);
    gload_lds16(gb0 + k0, lB0);
    gload_lds16(gb1 + k0, lB1);
    __syncthreads();

    const bf16x8* Ap = (const bf16x8*)As;
    const bf16x8* Bp = (const bf16x8*)Bs;
    bf16x8 af[2], bfr[4];
#pragma unroll
    for (int m = 0; m < 2; m++) af[m] = Ap[(wr + m * 16 + rl) * 4 + kc];
#pragma unroll
    for (int n = 0; n < 4; n++) bfr[n] = Bp[(wc + n * 16 + rl) * 4 + kc];
#pragma unroll
    for (int m = 0; m < 2; m++)
#pragma unroll
      for (int n = 0; n < 4; n++)
        acc[m][n] = __builtin_amdgcn_mfma_f32_16x16x32_bf16(af[m], bfr[n], acc[m][n], 0, 0, 0);
    __syncthreads();
  }

  int rj = lane >> 4, cl = lane & 15;
#pragma unroll
  for (int m = 0; m < 2; m++)
#pragma unroll
    for (int n = 0; n < 4; n++)
#pragma unroll
      for (int j = 0; j < 4; j++) {
        int r = row0 + wr + m * 16 + rj * 4 + j;
        int c = col0 + wc + n * 16 + cl;
        C[(size_t)r * DIM + c] = acc[m][n][j];
      }
}

// ---------------- combine: out[t] = rout[r0] + rout[r1] + rout[shared] -------------------------
__global__ __launch_bounds__(256) void combine(const float* __restrict__ rout,
                                               const int* __restrict__ row_of,
                                               const int* __restrict__ base8,
                                               float* __restrict__ out) {
  int t = blockIdx.x;
  int c = threadIdx.x * 4;
  int r0 = row_of[2 * t], r1 = row_of[2 * t + 1];
  int rs = *base8 + t;
  float4 v0 = *(const float4*)(rout + (size_t)r0 * DIM + c);
  float4 v1 = *(const float4*)(rout + (size_t)r1 * DIM + c);
  float4 v2 = *(const float4*)(rout + (size_t)rs * DIM + c);
  float4 o;
  o.x = v0.x + v1.x + v2.x;
  o.y = v0.y + v1.y + v2.y;
  o.z = v0.z + v1.z + v2.z;
  o.w = v0.w + v1.w + v2.w;
  *(float4*)(out + (size_t)t * DIM + c) = o;
}

extern "C" void kernel_launch(void* const* d_in, const int* in_sizes, int n_in,
                              void* d_out, int out_size, void* d_ws, size_t ws_size,
                              hipStream_t stream) {
  const float* x   = (const float*)d_in[0];
  const float* gw  = (const float*)d_in[1];
  const float* w1  = (const float*)d_in[2];
  const float* w2  = (const float*)d_in[3];
  const float* w3  = (const float*)d_in[4];
  const float* w1s = (const float*)d_in[5];
  const float* w2s = (const float*)d_in[6];
  const float* w3s = (const float*)d_in[7];
  float* out = (float*)d_out;
  char* ws = (char*)d_ws;

  const size_t MB = 1ull << 20;
  unsigned short* w1t  = (unsigned short*)(ws + 0 * MB);    // 16MB [8][1024][1024] B^T bf16
  unsigned short* w3t  = (unsigned short*)(ws + 16 * MB);   // 16MB
  unsigned short* w2t  = (unsigned short*)(ws + 32 * MB);   // 16MB
  unsigned short* w1st = (unsigned short*)(ws + 48 * MB);   // 2MB
  unsigned short* w3st = (unsigned short*)(ws + 50 * MB);   // 2MB
  unsigned short* w2st = (unsigned short*)(ws + 52 * MB);   // 2MB
  unsigned short* xbf  = (unsigned short*)(ws + 54 * MB);   // 4MB+  [NTOK+1][1024] bf16
  unsigned short* hbuf = (unsigned short*)(ws + 60 * MB);   // 16MB [8192][1024] bf16
  float* rout = (float*)(ws + 76 * MB);                     // 32MB [8192][1024] fp32
  char* meta = ws + 108 * MB;
  int*   e0p    = (int*)meta;
  int*   e1p    = e0p + NTOK;
  float* s0p    = (float*)(e1p + NTOK);
  float* s1p    = s0p + NTOK;
  int*   gtok   = (int*)(s1p + NTOK);
  float* gsc    = (float*)(gtok + ROWS_CAP);
  int*   row_of = (int*)(gsc + ROWS_CAP);
  int*   tile_e = row_of + NENT;
  int*   tile_r0= tile_e + MAX_TILES;
  int*   ntiles = tile_r0 + MAX_TILES;
  int*   base8  = ntiles + 1;

  cast_x<<<NTOK + 1, 256, 0, stream>>>(x, xbf);
  router<<<NTOK, 64, 0, stream>>>(x, gw, e0p, e1p, s0p, s1p);
  build_groups<<<1, 256, 0, stream>>>(e0p, e1p, s0p, s1p, gtok, gsc, row_of,
                                      tile_e, tile_r0, ntiles, base8);
  transpose_all<<<dim3(32, 4, 27), 256, 0, stream>>>(
      w1, w3, w2, w1s, w3s, w2s, w1t, w3t, w2t, w1st, w3st, w2st);

  dim3 gg(8, MAX_TILES);
  gemm13<<<gg, 256, 0, stream>>>(xbf, w1t, w1st, w3t, w3st, hbuf,
                                 gtok, gsc, tile_e, tile_r0, ntiles);
  gemm2<<<gg, 256, 0, stream>>>(hbuf, w2t, w2st, rout, tile_e, tile_r0, ntiles);

  combine<<<NTOK, 256, 0, stream>>>(rout, row_of, base8, out);
}

// Round 6
// 136.954 us; speedup vs baseline: 1.1251x; 1.1251x over previous
//
#include <hip/hip_runtime.h>
#include <hip/hip_bf16.h>

// MoE top-2 + shared expert, bf16 MFMA path. Round 6.
// vs R3 (best, 129.8us): GEMM K-loop now counted-vmcnt double-buffered
// (raw s_barrier + s_waitcnt vmcnt(L), never 0 in-loop) so next-tile
// global_load_lds stay in flight across the barrier (T3/T4 mechanism; R4's
// __syncthreads dbuf drained them -> regressed). Plus read-side kc^=row&3
// LDS swizzle with inverse-swizzled global source (8-way -> 4-way conflict).
// 128x128 tiles, 128-row padding, col-fastest grid. No atomics.

#define DIM 1024
#define NTOK 2048
#define NEXP 8
#define NENT 4096          // NTOK * 2
#define ROWS_CAP 8192      // padded grouped rows upper bound
#define MAX_TILES 64
#define MM (DIM * DIM)

typedef float f32x4 __attribute__((ext_vector_type(4)));
typedef __bf16 bf16x8 __attribute__((ext_vector_type(8)));

__device__ __forceinline__ unsigned short f2bf(float f) {
  unsigned int u = __builtin_bit_cast(unsigned int, f);
  unsigned int r = u + 0x7FFFu + ((u >> 16) & 1u);   // RNE
  return (unsigned short)(r >> 16);
}
__device__ __forceinline__ void gload_lds16(const unsigned short* g, unsigned short* l) {
  __builtin_amdgcn_global_load_lds((__attribute__((address_space(1))) const void*)g,
                                   (__attribute__((address_space(3))) void*)l, 16, 0, 0);
}

// ---------------- x -> bf16 (row NTOK is an all-zero pad row) ----------------------------------
__global__ __launch_bounds__(256) void cast_x(const float* __restrict__ x,
                                              unsigned short* __restrict__ xbf) {
  int r = blockIdx.x;                 // 0..NTOK
  int c = threadIdx.x * 4;
  ushort4 o;
  if (r < NTOK) {
    float4 v = *(const float4*)(x + (size_t)r * DIM + c);
    o.x = f2bf(v.x); o.y = f2bf(v.y); o.z = f2bf(v.z); o.w = f2bf(v.w);
  } else {
    o.x = o.y = o.z = o.w = 0;
  }
  *(ushort4*)(xbf + (size_t)r * DIM + c) = o;
}

// ---------------- weight transpose+cast: dst[n][k] = bf16(src[k][n]), 27 z-slices --------------
__global__ __launch_bounds__(256) void transpose_all(
    const float* __restrict__ w1, const float* __restrict__ w3, const float* __restrict__ w2,
    const float* __restrict__ w1s, const float* __restrict__ w3s, const float* __restrict__ w2s,
    unsigned short* __restrict__ w1t, unsigned short* __restrict__ w3t,
    unsigned short* __restrict__ w2t, unsigned short* __restrict__ w1st,
    unsigned short* __restrict__ w3st, unsigned short* __restrict__ w2st) {
  __shared__ unsigned short u[32][264];   // [n][k], pad 8 -> 528B row stride
  int z = blockIdx.z;
  const float* src; unsigned short* dst;
  if (z < 8)       { src = w1 + (size_t)z * MM;        dst = w1t + (size_t)z * MM; }
  else if (z < 16) { src = w3 + (size_t)(z - 8) * MM;  dst = w3t + (size_t)(z - 8) * MM; }
  else if (z < 24) { src = w2 + (size_t)(z - 16) * MM; dst = w2t + (size_t)(z - 16) * MM; }
  else if (z == 24){ src = w1s; dst = w1st; }
  else if (z == 25){ src = w3s; dst = w3st; }
  else             { src = w2s; dst = w2st; }
  int r0 = blockIdx.y * 256, c0 = blockIdx.x * 32;
  int tid = threadIdx.x;
  int rr = tid >> 3;              // 0..31
  int cc = (tid & 7) * 4;         // 0,4,..,28
#pragma unroll
  for (int i = 0; i < 8; i++) {
    int r = rr + i * 32;
    float4 v = *(const float4*)(src + (size_t)(r0 + r) * DIM + c0 + cc);
    u[cc + 0][r] = f2bf(v.x);
    u[cc + 1][r] = f2bf(v.y);
    u[cc + 2][r] = f2bf(v.z);
    u[cc + 3][r] = f2bf(v.w);
  }
  __syncthreads();
  int rb = (tid & 31) * 8;        // k offset, 16B chunks
  int cb = tid >> 5;              // 0..7
#pragma unroll
  for (int i = 0; i < 4; i++) {
    int c = cb + i * 8;
    uint4 v = *(const uint4*)&u[c][rb];
    *(uint4*)(dst + (size_t)(c0 + c) * DIM + r0 + rb) = v;
  }
}

// ---------------- router: fp32 logits -> softmax -> top-2 --------------------------------------
__global__ __launch_bounds__(64) void router(const float* __restrict__ x,
                                             const float* __restrict__ gw,
                                             int* __restrict__ e0, int* __restrict__ e1,
                                             float* __restrict__ s0, float* __restrict__ s1) {
  int t = blockIdx.x;
  int lane = threadIdx.x;
  const float* xr = x + (size_t)t * DIM;
  float acc[NEXP];
#pragma unroll
  for (int e = 0; e < NEXP; e++) acc[e] = 0.f;
  for (int i = 0; i < DIM / 64; i++) {
    float xv = xr[i * 64 + lane];
#pragma unroll
    for (int e = 0; e < NEXP; e++) acc[e] += xv * gw[e * DIM + i * 64 + lane];
  }
#pragma unroll
  for (int e = 0; e < NEXP; e++) {
    float v = acc[e];
    for (int o = 32; o > 0; o >>= 1) v += __shfl_xor(v, o);
    acc[e] = v;
  }
  if (lane == 0) {
    float m = acc[0];
#pragma unroll
    for (int e = 1; e < NEXP; e++) m = fmaxf(m, acc[e]);
    float ex[NEXP]; float Z = 0.f;
#pragma unroll
    for (int e = 0; e < NEXP; e++) { ex[e] = __expf(acc[e] - m); Z += ex[e]; }
    float inv = 1.f / Z;
    float sc[NEXP];
#pragma unroll
    for (int e = 0; e < NEXP; e++) sc[e] = ex[e] * inv;
    int b0 = 0; float v0 = sc[0];
#pragma unroll
    for (int e = 1; e < NEXP; e++) if (sc[e] > v0) { v0 = sc[e]; b0 = e; }
    int b1 = -1; float v1 = -1.f;
#pragma unroll
    for (int e = 0; e < NEXP; e++) if (e != b0 && sc[e] > v1) { v1 = sc[e]; b1 = e; }
    e0[t] = b0; e1[t] = b1; s0[t] = v0; s1[t] = v1;
  }
}

// ---------------- deterministic grouped build: packed uint4 scan (128-row padding) -------------
__global__ __launch_bounds__(256) void build_groups(
    const int* __restrict__ e0, const int* __restrict__ e1,
    const float* __restrict__ s0, const float* __restrict__ s1,
    int* __restrict__ gtok, float* __restrict__ gsc, int* __restrict__ row_of,
    int* __restrict__ tile_e, int* __restrict__ tile_r0, int* __restrict__ ntiles,
    int* __restrict__ base8out) {
  __shared__ unsigned int wsum[4][4];
  __shared__ int offl[256][NEXP];
  __shared__ int lrl[256][NEXP];
  int t = threadIdx.x, lane = t & 63, wave = t >> 6;

  for (int i = t; i < ROWS_CAP; i += 256) { gtok[i] = NTOK; gsc[i] = 0.f; }  // pad -> zero row

  unsigned int pc[4] = {0, 0, 0, 0};
#pragma unroll
  for (int i = 0; i < 16; i++) {
    int ent = t * 16 + i;
    int tok = ent >> 1;
    int e = (ent & 1) ? e1[tok] : e0[tok];
    unsigned int add = 1u << ((e & 1) * 16);
    int c = e >> 1;
    if (c == 0) pc[0] += add; else if (c == 1) pc[1] += add;
    else if (c == 2) pc[2] += add; else pc[3] += add;
  }
  unsigned int incl[4] = {pc[0], pc[1], pc[2], pc[3]};
#pragma unroll
  for (int o = 1; o < 64; o <<= 1) {
    unsigned int u0 = __shfl_up(incl[0], o), u1 = __shfl_up(incl[1], o);
    unsigned int u2 = __shfl_up(incl[2], o), u3 = __shfl_up(incl[3], o);
    if (lane >= o) { incl[0] += u0; incl[1] += u1; incl[2] += u2; incl[3] += u3; }
  }
  if (lane == 63) { wsum[wave][0] = incl[0]; wsum[wave][1] = incl[1];
                    wsum[wave][2] = incl[2]; wsum[wave][3] = incl[3]; }
  __syncthreads();
  unsigned int T[4], pre[4] = {0, 0, 0, 0};
#pragma unroll
  for (int c = 0; c < 4; c++)
    T[c] = wsum[0][c] + wsum[1][c] + wsum[2][c] + wsum[3][c];
#pragma unroll
  for (int w = 0; w < 3; w++)
    if (wave > w) { pre[0] += wsum[w][0]; pre[1] += wsum[w][1];
                    pre[2] += wsum[w][2]; pre[3] += wsum[w][3]; }
  int base[NEXP + 1];
  {
    int b = 0;
#pragma unroll
    for (int e = 0; e < NEXP; e++) {
      int tot = (int)((T[e >> 1] >> ((e & 1) * 16)) & 0xFFFFu);
      base[e] = b; b += (tot + 127) & ~127;
    }
    base[NEXP] = b;
  }
#pragma unroll
  for (int e = 0; e < NEXP; e++) {
    unsigned int ex = (incl[e >> 1] + pre[e >> 1] - pc[e >> 1]);
    offl[t][e] = (int)((ex >> ((e & 1) * 16)) & 0xFFFFu);
    lrl[t][e] = 0;
  }
  if (t == 0) {
    int nt = 0;
#pragma unroll
    for (int e = 0; e < NEXP; e++) {
      int tot = (int)((T[e >> 1] >> ((e & 1) * 16)) & 0xFFFFu);
      int ntl = (tot + 127) >> 7;
      for (int i = 0; i < ntl; i++) { tile_e[nt] = e; tile_r0[nt] = base[e] + i * 128; nt++; }
    }
    for (int i = 0; i < NTOK / 128; i++) { tile_e[nt] = NEXP; tile_r0[nt] = base[NEXP] + i * 128; nt++; }
    *ntiles = nt;
    *base8out = base[NEXP];
  }
  __syncthreads();   // gtok/gsc clear complete before scatter

#pragma unroll
  for (int i = 0; i < 16; i++) {
    int ent = t * 16 + i;
    int tok = ent >> 1;
    int k = ent & 1;
    int e = k ? e1[tok] : e0[tok];
    float s = k ? s1[tok] : s0[tok];
    int pos = base[e] + offl[t][e] + lrl[t][e];
    lrl[t][e]++;
    gtok[pos] = tok; gsc[pos] = s; row_of[ent] = pos;
  }
  for (int i = t; i < NTOK; i += 256) { gtok[base[NEXP] + i] = i; gsc[base[NEXP] + i] = 1.0f; }
}

// ------- fused grouped GEMM: h = silu(s*(A*W1_e)) * (s*(A*W3_e)), A gathered from xbf ----------
// Counted-vmcnt double-buffer: next tile's 6 loads stay in flight across the barrier.
__global__ __launch_bounds__(256) void gemm13(
    const unsigned short* __restrict__ xbf,
    const unsigned short* __restrict__ W1, const unsigned short* __restrict__ W1s,
    const unsigned short* __restrict__ W3, const unsigned short* __restrict__ W3s,
    unsigned short* __restrict__ H,
    const int* __restrict__ gtok, const float* __restrict__ gsc,
    const int* __restrict__ tile_e, const int* __restrict__ tile_r0,
    const int* __restrict__ ntiles) {
  if ((int)blockIdx.y >= *ntiles) return;
  int e = tile_e[blockIdx.y];
  int row0 = tile_r0[blockIdx.y];
  int col0 = blockIdx.x * 128;
  const unsigned short* B1 = (e < NEXP) ? (W1 + (size_t)e * MM) : W1s;
  const unsigned short* B3 = (e < NEXP) ? (W3 + (size_t)e * MM) : W3s;

  __shared__ __align__(16) unsigned short As[2 * 4096];   // 16KB (2 bufs)
  __shared__ __align__(16) unsigned short Bs1[2 * 4096];
  __shared__ __align__(16) unsigned short Bs3[2 * 4096];
  __shared__ float ss[128];

  int tid = threadIdx.x;
  int wave = tid >> 6, lane = tid & 63;
  int wr = (wave >> 1) * 64, wc = (wave & 1) * 64;

  if (tid < 128) ss[tid] = gsc[row0 + tid];   // consumed after many barriers

  f32x4 acc1[4][4], acc3[4][4];
#pragma unroll
  for (int m = 0; m < 4; m++)
#pragma unroll
    for (int n = 0; n < 4; n++) { acc1[m][n] = f32x4{0.f,0.f,0.f,0.f}; acc3[m][n] = f32x4{0.f,0.f,0.f,0.f}; }

  int li0 = (wave * 2 + 0) * 64 + lane;   // 16B-chunk index
  int li1 = (wave * 2 + 1) * 64 + lane;
  // inverse-swizzled global source: chunk kc_src = (li&3) ^ (row&3)  (involution)
  int ks0 = ((li0 & 3) ^ ((li0 >> 2) & 3)) * 8;
  int ks1 = ((li1 & 3) ^ ((li1 >> 2) & 3)) * 8;
  const unsigned short* ga0 = xbf + (size_t)gtok[row0 + (li0 >> 2)] * DIM + ks0;
  const unsigned short* ga1 = xbf + (size_t)gtok[row0 + (li1 >> 2)] * DIM + ks1;
  const unsigned short* gb10 = B1 + (size_t)(col0 + (li0 >> 2)) * DIM + ks0;
  const unsigned short* gb11 = B1 + (size_t)(col0 + (li1 >> 2)) * DIM + ks1;
  const unsigned short* gb30 = B3 + (size_t)(col0 + (li0 >> 2)) * DIM + ks0;
  const unsigned short* gb31 = B3 + (size_t)(col0 + (li1 >> 2)) * DIM + ks1;
  int off0 = (wave * 2 + 0) * 512;        // wave-uniform LDS base (+lane*16B by HW)
  int off1 = (wave * 2 + 1) * 512;

  int kc = lane >> 4, rl = lane & 15;
  int kr = kc ^ (rl & 3);                 // swizzled read chunk

#define STAGE13(P, K)                                   \
  { unsigned short* a_ = As + (P) * 4096;               \
    unsigned short* b1_ = Bs1 + (P) * 4096;             \
    unsigned short* b3_ = Bs3 + (P) * 4096;             \
    gload_lds16(ga0 + (K), a_ + off0);                  \
    gload_lds16(ga1 + (K), a_ + off1);                  \
    gload_lds16(gb10 + (K), b1_ + off0);                \
    gload_lds16(gb11 + (K), b1_ + off1);                \
    gload_lds16(gb30 + (K), b3_ + off0);                \
    gload_lds16(gb31 + (K), b3_ + off1); }

#define COMPUTE13(P)                                                       \
  { const bf16x8* Ap  = (const bf16x8*)(As + (P) * 4096);                  \
    const bf16x8* B1p = (const bf16x8*)(Bs1 + (P) * 4096);                 \
    const bf16x8* B3p = (const bf16x8*)(Bs3 + (P) * 4096);                 \
    bf16x8 af[4], b1f[4], b3f[4];                                          \
    _Pragma("unroll")                                                      \
    for (int m = 0; m < 4; m++) af[m] = Ap[(wr + m * 16 + rl) * 4 + kr];   \
    _Pragma("unroll")                                                      \
    for (int n = 0; n < 4; n++) { b1f[n] = B1p[(wc + n * 16 + rl) * 4 + kr]; \
                                  b3f[n] = B3p[(wc + n * 16 + rl) * 4 + kr]; } \
    _Pragma("unroll")                                                      \
    for (int m = 0; m < 4; m++)                                            \
      _Pragma("unroll")                                                    \
      for (int n = 0; n < 4; n++) {                                        \
        acc1[m][n] = __builtin_amdgcn_mfma_f32_16x16x32_bf16(af[m], b1f[n], acc1[m][n], 0, 0, 0); \
        acc3[m][n] = __builtin_amdgcn_mfma_f32_16x16x32_bf16(af[m], b3f[n], acc3[m][n], 0, 0, 0); \
      } }

  STAGE13(0, 0);
  for (int t = 0; t < DIM / 32; t++) {
    int c = t & 1;
    if (t + 1 < DIM / 32) {
      STAGE13(c ^ 1, (t + 1) * 32);
      asm volatile("s_waitcnt vmcnt(6)" ::: "memory");   // tile-t loads landed; t+1's fly on
    } else {
      asm volatile("s_waitcnt vmcnt(0)" ::: "memory");
    }
    __builtin_amdgcn_s_barrier();     // all waves' tile-t loads complete
    COMPUTE13(c);
    __builtin_amdgcn_s_barrier();     // all reads of buf c done before t+2 overwrites it
  }

  int rj = lane >> 4, cl = lane & 15;
#pragma unroll
  for (int m = 0; m < 4; m++)
#pragma unroll
    for (int n = 0; n < 4; n++)
#pragma unroll
      for (int j = 0; j < 4; j++) {
        int lr = wr + m * 16 + rj * 4 + j;
        float s = ss[lr];
        float a = s * acc1[m][n][j];
        float g = s * acc3[m][n][j];
        float si = a / (1.f + __expf(-a));
        H[(size_t)(row0 + lr) * DIM + (col0 + wc + n * 16 + cl)] = f2bf(si * g);
      }
}

// ---------------- grouped GEMM: rout = H * W2_e (fp32 out), counted-vmcnt dbuf -----------------
__global__ __launch_bounds__(256) void gemm2(
    const unsigned short* __restrict__ A, const unsigned short* __restrict__ W,
    const unsigned short* __restrict__ Wsh, float* __restrict__ C,
    const int* __restrict__ tile_e, const int* __restrict__ tile_r0,
    const int* __restrict__ ntiles) {
  if ((int)blockIdx.y >= *ntiles) return;
  int e = tile_e[blockIdx.y];
  int row0 = tile_r0[blockIdx.y];
  int col0 = blockIdx.x * 128;
  const unsigned short* B = (e < NEXP) ? (W + (size_t)e * MM) : Wsh;

  __shared__ __align__(16) unsigned short As[2 * 4096];
  __shared__ __align__(16) unsigned short Bs[2 * 4096];

  int tid = threadIdx.x;
  int wave = tid >> 6, lane = tid & 63;
  int wr = (wave >> 1) * 64, wc = (wave & 1) * 64;

  f32x4 acc[4][4];
#pragma unroll
  for (int m = 0; m < 4; m++)
#pragma unroll
    for (int n = 0; n < 4; n++) acc[m][n] = f32x4{0.f, 0.f, 0.f, 0.f};

  int li0 = (wave * 2 + 0) * 64 + lane;
  int li1 = (wave * 2 + 1) * 64 + lane;
  int ks0 = ((li0 & 3) ^ ((li0 >> 2) & 3)) * 8;
  int ks1 = ((li1 & 3) ^ ((li1 >> 2) & 3)) * 8;
  const unsigned short* ga0 = A + (size_t)(row0 + (li0 >> 2)) * DIM + ks0;
  const unsigned short* ga1 = A + (size_t)(row0 + (li1 >> 2)) * DIM + ks1;
  const unsigned short* gb0 = B + (size_t)(col0 + (li0 >> 2)) * DIM + ks0;
  const unsigned short* gb1 = B + (size_t)(col0 + (li1 >> 2)) * DIM + ks1;
  int off0 = (wave * 2 + 0) * 512;
  int off1 = (wave * 2 + 1) * 512;

  int kc = lane >> 4, rl = lane & 15;
  int kr = kc ^ (rl & 3);

#define STAGE2(P, K)                                   \
  { unsigned short* a_ = As + (P) * 4096;              \
    unsigned short* b_ = Bs + (P) * 4096;              \
    gload_lds16(ga0 + (K), a_ + off0);                 \
    gload_lds16(ga1 + (K), a_ + off1);                 \
    gload_lds16(gb0 + (K), b_ + off0);                 \
    gload_lds16(gb1 + (K), b_ + off1); }

#define COMPUTE2(P)                                                        \
  { const bf16x8* Ap = (const bf16x8*)(As + (P) * 4096);                   \
    const bf16x8* Bp = (const bf16x8*)(Bs + (P) * 4096);                   \
    bf16x8 af[4], bfr[4];                                                  \
    _Pragma("unroll")                                                      \
    for (int m = 0; m < 4; m++) af[m] = Ap[(wr + m * 16 + rl) * 4 + kr];   \
    _Pragma("unroll")                                                      \
    for (int n = 0; n < 4; n++) bfr[n] = Bp[(wc + n * 16 + rl) * 4 + kr];  \
    _Pragma("unroll")                                                      \
    for (int m = 0; m < 4; m++)                                            \
      _Pragma("unroll")                                                    \
      for (int n = 0; n < 4; n++)                                          \
        acc[m][n] = __builtin_amdgcn_mfma_f32_16x16x32_bf16(af[m], bfr[n], acc[m][n], 0, 0, 0); }

  STAGE2(0, 0);
  for (int t = 0; t < DIM / 32; t++) {
    int c = t & 1;
    if (t + 1 < DIM / 32) {
      STAGE2(c ^ 1, (t + 1) * 32);
      asm volatile("s_waitcnt vmcnt(4)" ::: "memory");
    } else {
      asm volatile("s_waitcnt vmcnt(0)" ::: "memory");
    }
    __builtin_amdgcn_s_barrier();
    COMPUTE2(c);
    __builtin_amdgcn_s_barrier();
  }

  int rj = lane >> 4, cl = lane & 15;
#pragma unroll
  for (int m = 0; m < 4; m++)
#pragma unroll
    for (int n = 0; n < 4; n++)
#pragma unroll
      for (int j = 0; j < 4; j++) {
        int r = row0 + wr + m * 16 + rj * 4 + j;
        int c = col0 + wc + n * 16 + cl;
        C[(size_t)r * DIM + c] = acc[m][n][j];
      }
}

// ---------------- combine: out[t] = rout[r0] + rout[r1] + rout[shared] -------------------------
__global__ __launch_bounds__(256) void combine(const float* __restrict__ rout,
                                               const int* __restrict__ row_of,
                                               const int* __restrict__ base8,
                                               float* __restrict__ out) {
  int t = blockIdx.x;
  int c = threadIdx.x * 4;
  int r0 = row_of[2 * t], r1 = row_of[2 * t + 1];
  int rs = *base8 + t;
  float4 v0 = *(const float4*)(rout + (size_t)r0 * DIM + c);
  float4 v1 = *(const float4*)(rout + (size_t)r1 * DIM + c);
  float4 v2 = *(const float4*)(rout + (size_t)rs * DIM + c);
  float4 o;
  o.x = v0.x + v1.x + v2.x;
  o.y = v0.y + v1.y + v2.y;
  o.z = v0.z + v1.z + v2.z;
  o.w = v0.w + v1.w + v2.w;
  *(float4*)(out + (size_t)t * DIM + c) = o;
}

extern "C" void kernel_launch(void* const* d_in, const int* in_sizes, int n_in,
                              void* d_out, int out_size, void* d_ws, size_t ws_size,
                              hipStream_t stream) {
  const float* x   = (const float*)d_in[0];
  const float* gw  = (const float*)d_in[1];
  const float* w1  = (const float*)d_in[2];
  const float* w2  = (const float*)d_in[3];
  const float* w3  = (const float*)d_in[4];
  const float* w1s = (const float*)d_in[5];
  const float* w2s = (const float*)d_in[6];
  const float* w3s = (const float*)d_in[7];
  float* out = (float*)d_out;
  char* ws = (char*)d_ws;

  const size_t MB = 1ull << 20;
  unsigned short* w1t  = (unsigned short*)(ws + 0 * MB);    // 16MB [8][1024][1024] B^T bf16
  unsigned short* w3t  = (unsigned short*)(ws + 16 * MB);   // 16MB
  unsigned short* w2t  = (unsigned short*)(ws + 32 * MB);   // 16MB
  unsigned short* w1st = (unsigned short*)(ws + 48 * MB);   // 2MB
  unsigned short* w3st = (unsigned short*)(ws + 50 * MB);   // 2MB
  unsigned short* w2st = (unsigned short*)(ws + 52 * MB);   // 2MB
  unsigned short* xbf  = (unsigned short*)(ws + 54 * MB);   // 4MB+  [NTOK+1][1024] bf16
  unsigned short* hbuf = (unsigned short*)(ws + 60 * MB);   // 16MB [8192][1024] bf16
  float* rout = (float*)(ws + 76 * MB);                     // 32MB [8192][1024] fp32
  char* meta = ws + 108 * MB;
  int*   e0p    = (int*)meta;
  int*   e1p    = e0p + NTOK;
  float* s0p    = (float*)(e1p + NTOK);
  float* s1p    = s0p + NTOK;
  int*   gtok   = (int*)(s1p + NTOK);
  float* gsc    = (float*)(gtok + ROWS_CAP);
  int*   row_of = (int*)(gsc + ROWS_CAP);
  int*   tile_e = row_of + NENT;
  int*   tile_r0= tile_e + MAX_TILES;
  int*   ntiles = tile_r0 + MAX_TILES;
  int*   base8  = ntiles + 1;

  cast_x<<<NTOK + 1, 256, 0, stream>>>(x, xbf);
  router<<<NTOK, 64, 0, stream>>>(x, gw, e0p, e1p, s0p, s1p);
  build_groups<<<1, 256, 0, stream>>>(e0p, e1p, s0p, s1p, gtok, gsc, row_of,
                                      tile_e, tile_r0, ntiles, base8);
  transpose_all<<<dim3(32, 4, 27), 256, 0, stream>>>(
      w1, w3, w2, w1s, w3s, w2s, w1t, w3t, w2t, w1st, w3st, w2st);

  dim3 gg(8, MAX_TILES);
  gemm13<<<gg, 256, 0, stream>>>(xbf, w1t, w1st, w3t, w3st, hbuf,
                                 gtok, gsc, tile_e, tile_r0, ntiles);
  gemm2<<<gg, 256, 0, stream>>>(hbuf, w2t, w2st, rout, tile_e, tile_r0, ntiles);

  combine<<<NTOK, 256, 0, stream>>>(rout, row_of, base8, out);
}

// Round 7
// 125.919 us; speedup vs baseline: 1.2237x; 1.0876x over previous
//
#include <hip/hip_runtime.h>
#include <hip/hip_bf16.h>

// MoE top-2 + shared expert, bf16 MFMA path. Round 7.
// vs R3 (prev best 129.8us): GEMMs go 256->512 threads (8 waves) on the SAME
// 128x128 tile — wave-tile 32x64, 3 gloads/thread — to lift waves/SIMD from
// ~1.2 to ~2.5-3 so stage/ds_read/MFMA phases overlap across waves (m114).
// K-loop stays the proven single-buffer 2-barrier form (R4/R6 pipelining both
// regressed). R6's read swizzle dropped (conflict count proved write-side).
// Router score applied to w1/w3 accumulators in fp32 (exact). No atomics.

#define DIM 1024
#define NTOK 2048
#define NEXP 8
#define NENT 4096          // NTOK * 2
#define ROWS_CAP 8192      // padded grouped rows upper bound
#define MAX_TILES 64
#define MM (DIM * DIM)

typedef float f32x4 __attribute__((ext_vector_type(4)));
typedef __bf16 bf16x8 __attribute__((ext_vector_type(8)));

__device__ __forceinline__ unsigned short f2bf(float f) {
  unsigned int u = __builtin_bit_cast(unsigned int, f);
  unsigned int r = u + 0x7FFFu + ((u >> 16) & 1u);   // RNE
  return (unsigned short)(r >> 16);
}
__device__ __forceinline__ void gload_lds16(const unsigned short* g, unsigned short* l) {
  __builtin_amdgcn_global_load_lds((__attribute__((address_space(1))) const void*)g,
                                   (__attribute__((address_space(3))) void*)l, 16, 0, 0);
}

// ---------------- x -> bf16 (row NTOK is an all-zero pad row) ----------------------------------
__global__ __launch_bounds__(256) void cast_x(const float* __restrict__ x,
                                              unsigned short* __restrict__ xbf) {
  int r = blockIdx.x;                 // 0..NTOK
  int c = threadIdx.x * 4;
  ushort4 o;
  if (r < NTOK) {
    float4 v = *(const float4*)(x + (size_t)r * DIM + c);
    o.x = f2bf(v.x); o.y = f2bf(v.y); o.z = f2bf(v.z); o.w = f2bf(v.w);
  } else {
    o.x = o.y = o.z = o.w = 0;
  }
  *(ushort4*)(xbf + (size_t)r * DIM + c) = o;
}

// ---------------- weight transpose+cast: dst[n][k] = bf16(src[k][n]), 27 z-slices --------------
__global__ __launch_bounds__(256) void transpose_all(
    const float* __restrict__ w1, const float* __restrict__ w3, const float* __restrict__ w2,
    const float* __restrict__ w1s, const float* __restrict__ w3s, const float* __restrict__ w2s,
    unsigned short* __restrict__ w1t, unsigned short* __restrict__ w3t,
    unsigned short* __restrict__ w2t, unsigned short* __restrict__ w1st,
    unsigned short* __restrict__ w3st, unsigned short* __restrict__ w2st) {
  __shared__ unsigned short u[32][264];   // [n][k], pad 8 -> 528B row stride
  int z = blockIdx.z;
  const float* src; unsigned short* dst;
  if (z < 8)       { src = w1 + (size_t)z * MM;        dst = w1t + (size_t)z * MM; }
  else if (z < 16) { src = w3 + (size_t)(z - 8) * MM;  dst = w3t + (size_t)(z - 8) * MM; }
  else if (z < 24) { src = w2 + (size_t)(z - 16) * MM; dst = w2t + (size_t)(z - 16) * MM; }
  else if (z == 24){ src = w1s; dst = w1st; }
  else if (z == 25){ src = w3s; dst = w3st; }
  else             { src = w2s; dst = w2st; }
  int r0 = blockIdx.y * 256, c0 = blockIdx.x * 32;
  int tid = threadIdx.x;
  int rr = tid >> 3;              // 0..31
  int cc = (tid & 7) * 4;         // 0,4,..,28
#pragma unroll
  for (int i = 0; i < 8; i++) {
    int r = rr + i * 32;
    float4 v = *(const float4*)(src + (size_t)(r0 + r) * DIM + c0 + cc);
    u[cc + 0][r] = f2bf(v.x);
    u[cc + 1][r] = f2bf(v.y);
    u[cc + 2][r] = f2bf(v.z);
    u[cc + 3][r] = f2bf(v.w);
  }
  __syncthreads();
  int rb = (tid & 31) * 8;        // k offset, 16B chunks
  int cb = tid >> 5;              // 0..7
#pragma unroll
  for (int i = 0; i < 4; i++) {
    int c = cb + i * 8;
    uint4 v = *(const uint4*)&u[c][rb];
    *(uint4*)(dst + (size_t)(c0 + c) * DIM + r0 + rb) = v;
  }
}

// ---------------- router: fp32 logits -> softmax -> top-2 --------------------------------------
__global__ __launch_bounds__(64) void router(const float* __restrict__ x,
                                             const float* __restrict__ gw,
                                             int* __restrict__ e0, int* __restrict__ e1,
                                             float* __restrict__ s0, float* __restrict__ s1) {
  int t = blockIdx.x;
  int lane = threadIdx.x;
  const float* xr = x + (size_t)t * DIM;
  float acc[NEXP];
#pragma unroll
  for (int e = 0; e < NEXP; e++) acc[e] = 0.f;
  for (int i = 0; i < DIM / 64; i++) {
    float xv = xr[i * 64 + lane];
#pragma unroll
    for (int e = 0; e < NEXP; e++) acc[e] += xv * gw[e * DIM + i * 64 + lane];
  }
#pragma unroll
  for (int e = 0; e < NEXP; e++) {
    float v = acc[e];
    for (int o = 32; o > 0; o >>= 1) v += __shfl_xor(v, o);
    acc[e] = v;
  }
  if (lane == 0) {
    float m = acc[0];
#pragma unroll
    for (int e = 1; e < NEXP; e++) m = fmaxf(m, acc[e]);
    float ex[NEXP]; float Z = 0.f;
#pragma unroll
    for (int e = 0; e < NEXP; e++) { ex[e] = __expf(acc[e] - m); Z += ex[e]; }
    float inv = 1.f / Z;
    float sc[NEXP];
#pragma unroll
    for (int e = 0; e < NEXP; e++) sc[e] = ex[e] * inv;
    int b0 = 0; float v0 = sc[0];
#pragma unroll
    for (int e = 1; e < NEXP; e++) if (sc[e] > v0) { v0 = sc[e]; b0 = e; }
    int b1 = -1; float v1 = -1.f;
#pragma unroll
    for (int e = 0; e < NEXP; e++) if (e != b0 && sc[e] > v1) { v1 = sc[e]; b1 = e; }
    e0[t] = b0; e1[t] = b1; s0[t] = v0; s1[t] = v1;
  }
}

// ---------------- deterministic grouped build: packed uint4 scan (128-row padding) -------------
__global__ __launch_bounds__(256) void build_groups(
    const int* __restrict__ e0, const int* __restrict__ e1,
    const float* __restrict__ s0, const float* __restrict__ s1,
    int* __restrict__ gtok, float* __restrict__ gsc, int* __restrict__ row_of,
    int* __restrict__ tile_e, int* __restrict__ tile_r0, int* __restrict__ ntiles,
    int* __restrict__ base8out) {
  __shared__ unsigned int wsum[4][4];
  __shared__ int offl[256][NEXP];
  __shared__ int lrl[256][NEXP];
  int t = threadIdx.x, lane = t & 63, wave = t >> 6;

  for (int i = t; i < ROWS_CAP; i += 256) { gtok[i] = NTOK; gsc[i] = 0.f; }  // pad -> zero row

  unsigned int pc[4] = {0, 0, 0, 0};
#pragma unroll
  for (int i = 0; i < 16; i++) {
    int ent = t * 16 + i;
    int tok = ent >> 1;
    int e = (ent & 1) ? e1[tok] : e0[tok];
    unsigned int add = 1u << ((e & 1) * 16);
    int c = e >> 1;
    if (c == 0) pc[0] += add; else if (c == 1) pc[1] += add;
    else if (c == 2) pc[2] += add; else pc[3] += add;
  }
  unsigned int incl[4] = {pc[0], pc[1], pc[2], pc[3]};
#pragma unroll
  for (int o = 1; o < 64; o <<= 1) {
    unsigned int u0 = __shfl_up(incl[0], o), u1 = __shfl_up(incl[1], o);
    unsigned int u2 = __shfl_up(incl[2], o), u3 = __shfl_up(incl[3], o);
    if (lane >= o) { incl[0] += u0; incl[1] += u1; incl[2] += u2; incl[3] += u3; }
  }
  if (lane == 63) { wsum[wave][0] = incl[0]; wsum[wave][1] = incl[1];
                    wsum[wave][2] = incl[2]; wsum[wave][3] = incl[3]; }
  __syncthreads();
  unsigned int T[4], pre[4] = {0, 0, 0, 0};
#pragma unroll
  for (int c = 0; c < 4; c++)
    T[c] = wsum[0][c] + wsum[1][c] + wsum[2][c] + wsum[3][c];
#pragma unroll
  for (int w = 0; w < 3; w++)
    if (wave > w) { pre[0] += wsum[w][0]; pre[1] += wsum[w][1];
                    pre[2] += wsum[w][2]; pre[3] += wsum[w][3]; }
  int base[NEXP + 1];
  {
    int b = 0;
#pragma unroll
    for (int e = 0; e < NEXP; e++) {
      int tot = (int)((T[e >> 1] >> ((e & 1) * 16)) & 0xFFFFu);
      base[e] = b; b += (tot + 127) & ~127;
    }
    base[NEXP] = b;
  }
#pragma unroll
  for (int e = 0; e < NEXP; e++) {
    unsigned int ex = (incl[e >> 1] + pre[e >> 1] - pc[e >> 1]);
    offl[t][e] = (int)((ex >> ((e & 1) * 16)) & 0xFFFFu);
    lrl[t][e] = 0;
  }
  if (t == 0) {
    int nt = 0;
#pragma unroll
    for (int e = 0; e < NEXP; e++) {
      int tot = (int)((T[e >> 1] >> ((e & 1) * 16)) & 0xFFFFu);
      int ntl = (tot + 127) >> 7;
      for (int i = 0; i < ntl; i++) { tile_e[nt] = e; tile_r0[nt] = base[e] + i * 128; nt++; }
    }
    for (int i = 0; i < NTOK / 128; i++) { tile_e[nt] = NEXP; tile_r0[nt] = base[NEXP] + i * 128; nt++; }
    *ntiles = nt;
    *base8out = base[NEXP];
  }
  __syncthreads();   // gtok/gsc clear complete before scatter

#pragma unroll
  for (int i = 0; i < 16; i++) {
    int ent = t * 16 + i;
    int tok = ent >> 1;
    int k = ent & 1;
    int e = k ? e1[tok] : e0[tok];
    float s = k ? s1[tok] : s0[tok];
    int pos = base[e] + offl[t][e] + lrl[t][e];
    lrl[t][e]++;
    gtok[pos] = tok; gsc[pos] = s; row_of[ent] = pos;
  }
  for (int i = t; i < NTOK; i += 256) { gtok[base[NEXP] + i] = i; gsc[base[NEXP] + i] = 1.0f; }
}

// ------- fused grouped GEMM: h = silu(s*(A*W1_e)) * (s*(A*W3_e)), A gathered from xbf ----------
// 512 threads / 8 waves on a 128x128 tile; wave-tile 32x64; 3 gloads/thread/step.
__global__ __launch_bounds__(512, 4) void gemm13(
    const unsigned short* __restrict__ xbf,
    const unsigned short* __restrict__ W1, const unsigned short* __restrict__ W1s,
    const unsigned short* __restrict__ W3, const unsigned short* __restrict__ W3s,
    unsigned short* __restrict__ H,
    const int* __restrict__ gtok, const float* __restrict__ gsc,
    const int* __restrict__ tile_e, const int* __restrict__ tile_r0,
    const int* __restrict__ ntiles) {
  if ((int)blockIdx.y >= *ntiles) return;
  int e = tile_e[blockIdx.y];
  int row0 = tile_r0[blockIdx.y];
  int col0 = blockIdx.x * 128;
  const unsigned short* B1 = (e < NEXP) ? (W1 + (size_t)e * MM) : W1s;
  const unsigned short* B3 = (e < NEXP) ? (W3 + (size_t)e * MM) : W3s;

  __shared__ __align__(16) unsigned short As[128 * 32];    // 8KB
  __shared__ __align__(16) unsigned short Bs1[128 * 32];   // 8KB
  __shared__ __align__(16) unsigned short Bs3[128 * 32];   // 8KB
  __shared__ float ss[128];

  int tid = threadIdx.x;
  int wave = tid >> 6, lane = tid & 63;
  int wrow = (wave & 3) * 32, wcol = (wave >> 2) * 64;

  if (tid < 128) ss[tid] = gsc[row0 + tid];   // synced by first K-loop barrier

  f32x4 acc1[2][4], acc3[2][4];
#pragma unroll
  for (int m = 0; m < 2; m++)
#pragma unroll
    for (int n = 0; n < 4; n++) { acc1[m][n] = f32x4{0.f,0.f,0.f,0.f}; acc3[m][n] = f32x4{0.f,0.f,0.f,0.f}; }

  // one 16B chunk per thread per buffer: chunk index = tid, row = tid>>2, k-chunk = tid&3
  int arow = tid >> 2, koff = (tid & 3) * 8;
  const unsigned short* ga  = xbf + (size_t)gtok[row0 + arow] * DIM + koff;   // per-lane gather
  const unsigned short* gb1 = B1 + (size_t)(col0 + arow) * DIM + koff;
  const unsigned short* gb3 = B3 + (size_t)(col0 + arow) * DIM + koff;
  unsigned short* lA  = As  + wave * 512;   // wave-uniform base; HW adds lane*16B
  unsigned short* lB1 = Bs1 + wave * 512;
  unsigned short* lB3 = Bs3 + wave * 512;

  int kc = lane >> 4, rl = lane & 15;

  for (int k0 = 0; k0 < DIM; k0 += 32) {
    gload_lds16(ga + k0, lA);
    gload_lds16(gb1 + k0, lB1);
    gload_lds16(gb3 + k0, lB3);
    __syncthreads();   // drains vmcnt before use

    const bf16x8* Ap  = (const bf16x8*)As;
    const bf16x8* B1p = (const bf16x8*)Bs1;
    const bf16x8* B3p = (const bf16x8*)Bs3;
    bf16x8 af[2], b1f[4], b3f[4];
#pragma unroll
    for (int m = 0; m < 2; m++) af[m] = Ap[(wrow + m * 16 + rl) * 4 + kc];
#pragma unroll
    for (int n = 0; n < 4; n++) { b1f[n] = B1p[(wcol + n * 16 + rl) * 4 + kc];
                                  b3f[n] = B3p[(wcol + n * 16 + rl) * 4 + kc]; }
#pragma unroll
    for (int m = 0; m < 2; m++)
#pragma unroll
      for (int n = 0; n < 4; n++) {
        acc1[m][n] = __builtin_amdgcn_mfma_f32_16x16x32_bf16(af[m], b1f[n], acc1[m][n], 0, 0, 0);
        acc3[m][n] = __builtin_amdgcn_mfma_f32_16x16x32_bf16(af[m], b3f[n], acc3[m][n], 0, 0, 0);
      }
    __syncthreads();   // before next stage overwrites LDS
  }

  int rj = lane >> 4, cl = lane & 15;
#pragma unroll
  for (int m = 0; m < 2; m++)
#pragma unroll
    for (int n = 0; n < 4; n++)
#pragma unroll
      for (int j = 0; j < 4; j++) {
        int lr = wrow + m * 16 + rj * 4 + j;
        float s = ss[lr];
        float a = s * acc1[m][n][j];
        float g = s * acc3[m][n][j];
        float si = a / (1.f + __expf(-a));
        H[(size_t)(row0 + lr) * DIM + (col0 + wcol + n * 16 + cl)] = f2bf(si * g);
      }
}

// ---------------- grouped GEMM: rout = H * W2_e (fp32 out); 512 threads ------------------------
__global__ __launch_bounds__(512, 4) void gemm2(
    const unsigned short* __restrict__ A, const unsigned short* __restrict__ W,
    const unsigned short* __restrict__ Wsh, float* __restrict__ C,
    const int* __restrict__ tile_e, const int* __restrict__ tile_r0,
    const int* __restrict__ ntiles) {
  if ((int)blockIdx.y >= *ntiles) return;
  int e = tile_e[blockIdx.y];
  int row0 = tile_r0[blockIdx.y];
  int col0 = blockIdx.x * 128;
  const unsigned short* B = (e < NEXP) ? (W + (size_t)e * MM) : Wsh;

  __shared__ __align__(16) unsigned short As[128 * 32];
  __shared__ __align__(16) unsigned short Bs[128 * 32];

  int tid = threadIdx.x;
  int wave = tid >> 6, lane = tid & 63;
  int wrow = (wave & 3) * 32, wcol = (wave >> 2) * 64;

  f32x4 acc[2][4];
#pragma unroll
  for (int m = 0; m < 2; m++)
#pragma unroll
    for (int n = 0; n < 4; n++) acc[m][n] = f32x4{0.f, 0.f, 0.f, 0.f};

  int arow = tid >> 2, koff = (tid & 3) * 8;
  const unsigned short* ga = A + (size_t)(row0 + arow) * DIM + koff;
  const unsigned short* gb = B + (size_t)(col0 + arow) * DIM + koff;
  unsigned short* lA = As + wave * 512;
  unsigned short* lB = Bs + wave * 512;

  int kc = lane >> 4, rl = lane & 15;

  for (int k0 = 0; k0 < DIM; k0 += 32) {
    gload_lds16(ga + k0, lA);
    gload_lds16(gb + k0, lB);
    __syncthreads();

    const bf16x8* Ap = (const bf16x8*)As;
    const bf16x8* Bp = (const bf16x8*)Bs;
    bf16x8 af[2], bfr[4];
#pragma unroll
    for (int m = 0; m < 2; m++) af[m] = Ap[(wrow + m * 16 + rl) * 4 + kc];
#pragma unroll
    for (int n = 0; n < 4; n++) bfr[n] = Bp[(wcol + n * 16 + rl) * 4 + kc];
#pragma unroll
    for (int m = 0; m < 2; m++)
#pragma unroll
      for (int n = 0; n < 4; n++)
        acc[m][n] = __builtin_amdgcn_mfma_f32_16x16x32_bf16(af[m], bfr[n], acc[m][n], 0, 0, 0);
    __syncthreads();
  }

  int rj = lane >> 4, cl = lane & 15;
#pragma unroll
  for (int m = 0; m < 2; m++)
#pragma unroll
    for (int n = 0; n < 4; n++)
#pragma unroll
      for (int j = 0; j < 4; j++) {
        int r = row0 + wrow + m * 16 + rj * 4 + j;
        int c = col0 + wcol + n * 16 + cl;
        C[(size_t)r * DIM + c] = acc[m][n][j];
      }
}

// ---------------- combine: out[t] = rout[r0] + rout[r1] + rout[shared] -------------------------
__global__ __launch_bounds__(256) void combine(const float* __restrict__ rout,
                                               const int* __restrict__ row_of,
                                               const int* __restrict__ base8,
                                               float* __restrict__ out) {
  int t = blockIdx.x;
  int c = threadIdx.x * 4;
  int r0 = row_of[2 * t], r1 = row_of[2 * t + 1];
  int rs = *base8 + t;
  float4 v0 = *(const float4*)(rout + (size_t)r0 * DIM + c);
  float4 v1 = *(const float4*)(rout + (size_t)r1 * DIM + c);
  float4 v2 = *(const float4*)(rout + (size_t)rs * DIM + c);
  float4 o;
  o.x = v0.x + v1.x + v2.x;
  o.y = v0.y + v1.y + v2.y;
  o.z = v0.z + v1.z + v2.z;
  o.w = v0.w + v1.w + v2.w;
  *(float4*)(out + (size_t)t * DIM + c) = o;
}

extern "C" void kernel_launch(void* const* d_in, const int* in_sizes, int n_in,
                              void* d_out, int out_size, void* d_ws, size_t ws_size,
                              hipStream_t stream) {
  const float* x   = (const float*)d_in[0];
  const float* gw  = (const float*)d_in[1];
  const float* w1  = (const float*)d_in[2];
  const float* w2  = (const float*)d_in[3];
  const float* w3  = (const float*)d_in[4];
  const float* w1s = (const float*)d_in[5];
  const float* w2s = (const float*)d_in[6];
  const float* w3s = (const float*)d_in[7];
  float* out = (float*)d_out;
  char* ws = (char*)d_ws;

  const size_t MB = 1ull << 20;
  unsigned short* w1t  = (unsigned short*)(ws + 0 * MB);    // 16MB [8][1024][1024] B^T bf16
  unsigned short* w3t  = (unsigned short*)(ws + 16 * MB);   // 16MB
  unsigned short* w2t  = (unsigned short*)(ws + 32 * MB);   // 16MB
  unsigned short* w1st = (unsigned short*)(ws + 48 * MB);   // 2MB
  unsigned short* w3st = (unsigned short*)(ws + 50 * MB);   // 2MB
  unsigned short* w2st = (unsigned short*)(ws + 52 * MB);   // 2MB
  unsigned short* xbf  = (unsigned short*)(ws + 54 * MB);   // 4MB+  [NTOK+1][1024] bf16
  unsigned short* hbuf = (unsigned short*)(ws + 60 * MB);   // 16MB [8192][1024] bf16
  float* rout = (float*)(ws + 76 * MB);                     // 32MB [8192][1024] fp32
  char* meta = ws + 108 * MB;
  int*   e0p    = (int*)meta;
  int*   e1p    = e0p + NTOK;
  float* s0p    = (float*)(e1p + NTOK);
  float* s1p    = s0p + NTOK;
  int*   gtok   = (int*)(s1p + NTOK);
  float* gsc    = (float*)(gtok + ROWS_CAP);
  int*   row_of = (int*)(gsc + ROWS_CAP);
  int*   tile_e = row_of + NENT;
  int*   tile_r0= tile_e + MAX_TILES;
  int*   ntiles = tile_r0 + MAX_TILES;
  int*   base8  = ntiles + 1;

  cast_x<<<NTOK + 1, 256, 0, stream>>>(x, xbf);
  router<<<NTOK, 64, 0, stream>>>(x, gw, e0p, e1p, s0p, s1p);
  build_groups<<<1, 256, 0, stream>>>(e0p, e1p, s0p, s1p, gtok, gsc, row_of,
                                      tile_e, tile_r0, ntiles, base8);
  transpose_all<<<dim3(32, 4, 27), 256, 0, stream>>>(
      w1, w3, w2, w1s, w3s, w2s, w1t, w3t, w2t, w1st, w3st, w2st);

  dim3 gg(8, MAX_TILES);
  gemm13<<<gg, 512, 0, stream>>>(xbf, w1t, w1st, w3t, w3st, hbuf,
                                 gtok, gsc, tile_e, tile_r0, ntiles);
  gemm2<<<gg, 512, 0, stream>>>(hbuf, w2t, w2st, rout, tile_e, tile_r0, ntiles);

  combine<<<NTOK, 256, 0, stream>>>(rout, row_of, base8, out);
}